// Round 4
// baseline (242.030 us; speedup 1.0000x reference)
//
#include <hip/hip_runtime.h>
#include <stdint.h>

// PerfeCT membership test — out[i] = +5 if query triple i's wrapped-int32 KEY
// matches any data triple's wrapped-int32 KEY, else -5.
//
// NUMERICS (verified absmax 0 across rounds): JAX x64 disabled -> buffers are
// INT32; the reference computes _triple_key in int32, which WRAPS. Membership
// = equality of wrapped 32-bit keys.
//
// PERF history:
//  R0: probe batching + bucketized table + nt stream: scan 77 -> ~63us.
//  R2: explicit stream pipeline: NEUTRAL (compiler already hoists).
//  R3: 8-wide + speculative 2-bucket loads, launch_bounds(512,4): compiler
//      allocated 64 VGPR (chasing 8 waves/EU the LDS cap forbids) and SPILLED
//      the probe arrays -> 31MB scratch writes on the critical chain. 72us.
//      Lesson: halved occupancy + 52MB parasitic traffic only cost +14% ->
//      the 8-wide batching works; spills ate it.
//  R4: same 8-wide structure, spill-free: drop speculative eB (-32 VGPR),
//      launch_bounds(512,2) raises VGPR cap to 256 so the allocator doesn't
//      force-fit 64. Expect ~100-128 VGPR, 2 blocks/CU (LDS-bound), 16 waves.
//      Events/triple ~0.45 vs R1's ~0.8.

#define EMPTY64     0xFFFFFFFFFFFFFFFFULL
#define BLOOM_WORDS 16384u                 // 64 KB, power of two
#define BLOOM_MASK  (BLOOM_WORDS - 1u)

typedef unsigned int       v4u   __attribute__((ext_vector_type(4)));
typedef unsigned long long v2u64 __attribute__((ext_vector_type(2)));

__device__ __forceinline__ uint32_t key32(uint32_t h, uint32_t r, uint32_t t) {
    return (h * 15000u + r) * 15000u + t;  // int32 wrap semantics via uint32
}

__device__ __forceinline__ uint64_t mix64(uint64_t x) {
    x ^= x >> 30; x *= 0xbf58476d1ce4e5b9ULL;
    x ^= x >> 27; x *= 0x94d049bb133111ebULL;
    x ^= x >> 31;
    return x;
}

// Clear table (to EMPTY) and bloom (to 0) with 16B stores.
__global__ void clear_ws(uint4* __restrict__ table4, unsigned n_table4,
                         uint4* __restrict__ bloom4, unsigned n_bloom4) {
    unsigned i = blockIdx.x * blockDim.x + threadIdx.x;
    if (i < n_table4) table4[i] = make_uint4(~0u, ~0u, ~0u, ~0u);
    if (i < n_bloom4) bloom4[i] = make_uint4(0u, 0u, 0u, 0u);
}

__global__ void insert_queries(const int* __restrict__ heads,
                               const int* __restrict__ rels,
                               const int* __restrict__ tails,
                               unsigned long long* __restrict__ table,
                               unsigned tmask,
                               uint32_t* __restrict__ g_bloom,
                               float* __restrict__ out,
                               int Q) {
    int i = blockIdx.x * blockDim.x + threadIdx.x;
    if (i >= Q) return;
    out[i] = -5.0f;  // default: not a member
    uint32_t key = key32((uint32_t)heads[i], (uint32_t)rels[i], (uint32_t)tails[i]);
    uint64_t mix = mix64(key);
    // blocked bloom: one word, two bits
    uint32_t bm = (1u << ((mix >> 46) & 31u)) | (1u << ((mix >> 51) & 31u));
    atomicOr(&g_bloom[(mix >> 32) & BLOOM_MASK], bm);
    // open-addressing insert, BUCKET-ALIGNED start (even slot) so the scan
    // can walk aligned 16B pairs. Slots only go EMPTY->occupied, so every
    // entry's probe path stays occupied -> pair-walk terminating at the first
    // EMPTY-containing bucket (evaluated inclusively) reaches all duplicates.
    uint64_t entry = (uint64_t)key | ((uint64_t)(unsigned)i << 32);
    unsigned slot = ((unsigned)mix & (tmask >> 1)) << 1;     // even
    for (unsigned step = 0; step <= tmask; ++step) {         // bounded
        if (atomicCAS(&table[slot], EMPTY64, (unsigned long long)entry) == EMPTY64) break;
        slot = (slot + 1u) & tmask;
    }
}

// Walk aligned 2-entry buckets from bucket b until a bucket containing an
// EMPTY slot; write +5 for every matching entry (dup queries each inserted).
__device__ __forceinline__ void probe_pairs(uint32_t key, unsigned b,
                                            const v2u64* __restrict__ tb,
                                            unsigned bmask,
                                            float* __restrict__ out) {
    for (unsigned step = 0; step <= bmask; ++step) {         // bounded
        v2u64 e = tb[b];
        bool le = (e.x == EMPTY64), he = (e.y == EMPTY64);
        if (!le && (uint32_t)e.x == key) out[e.x >> 32] = 5.0f;
        if (!he && (uint32_t)e.y == key) out[e.y >> 32] = 5.0f;
        if (le || he) return;
        b = (b + 1u) & bmask;
    }
}

__global__ __launch_bounds__(512, 2)   // min 2 waves/EU -> VGPR cap 256: no
                                       // forced spills; LDS still caps at
                                       // 2 blocks/CU (16 waves) if VGPR<=128.
void scan_data(const int* __restrict__ data, int N,
               const unsigned long long* __restrict__ table,
               unsigned tmask,
               const uint32_t* __restrict__ g_bloom,
               float* __restrict__ out) {
    __shared__ uint32_t bloom[BLOOM_WORDS];     // 64 KB
    {   // stage bloom into LDS (16B vector copies)
        const uint4* src = (const uint4*)g_bloom;
        uint4* dst = (uint4*)bloom;
        for (unsigned w = threadIdx.x; w < BLOOM_WORDS / 4; w += blockDim.x)
            dst[w] = src[w];
    }
    __syncthreads();

    const unsigned tid    = blockIdx.x * blockDim.x + threadIdx.x;
    const unsigned stride = gridDim.x * blockDim.x;
    const unsigned bmask  = tmask >> 1;                      // bucket-index mask
    const v2u64* tb = (const v2u64*)table;

    if ((N & 7) == 0) {
        const unsigned nch = (unsigned)(N >> 3);   // 8-triple chunks
        const v4u* h4 = (const v4u*)data;
        const v4u* r4 = (const v4u*)(data + (size_t)N);
        const v4u* t4 = (const v4u*)(data + 2 * (size_t)N);

        for (unsigned c = tid; c < nch; c += stride) {
            // 6 independent nt stream loads (96 B/lane in flight)
            v4u h0 = __builtin_nontemporal_load(&h4[2 * c]);
            v4u r0 = __builtin_nontemporal_load(&r4[2 * c]);
            v4u t0 = __builtin_nontemporal_load(&t4[2 * c]);
            v4u h1 = __builtin_nontemporal_load(&h4[2 * c + 1]);
            v4u r1 = __builtin_nontemporal_load(&r4[2 * c + 1]);
            v4u t1 = __builtin_nontemporal_load(&t4[2 * c + 1]);

            uint32_t k[8];
            k[0] = key32(h0.x, r0.x, t0.x); k[1] = key32(h0.y, r0.y, t0.y);
            k[2] = key32(h0.z, r0.z, t0.z); k[3] = key32(h0.w, r0.w, t0.w);
            k[4] = key32(h1.x, r1.x, t1.x); k[5] = key32(h1.y, r1.y, t1.y);
            k[6] = key32(h1.z, r1.z, t1.z); k[7] = key32(h1.w, r1.w, t1.w);

            bool d[8]; unsigned b[8];
#pragma unroll
            for (int j = 0; j < 8; ++j) {          // 8 batched LDS bloom tests
                uint64_t m  = mix64(k[j]);
                uint32_t w  = bloom[(uint32_t)(m >> 32) & BLOOM_MASK];
                uint32_t bm = (1u << ((m >> 46) & 31u)) | (1u << ((m >> 51) & 31u));
                d[j] = (w & bm) != bm;             // done = bloom reject
                b[j] = (unsigned)m & bmask;
            }

            // batched bucket rounds: all pending 16B loads issue together,
            // one wait per round. ~57% of lanes have >=1 survivor; expected
            // rounds/chunk ~1.6 at wave level. e[] is 32 VGPRs live (no eB).
            for (unsigned g = 0; g <= bmask; ++g) {
                bool any = false;
#pragma unroll
                for (int j = 0; j < 8; ++j) any = any || !d[j];
                if (!any) break;
                v2u64 e[8];
#pragma unroll
                for (int j = 0; j < 8; ++j) if (!d[j]) e[j] = tb[b[j]];
#pragma unroll
                for (int j = 0; j < 8; ++j) if (!d[j]) {
                    bool le = (e[j].x == EMPTY64), he = (e[j].y == EMPTY64);
                    if (!le && (uint32_t)e[j].x == k[j]) out[e[j].x >> 32] = 5.0f;
                    if (!he && (uint32_t)e[j].y == k[j]) out[e[j].y >> 32] = 5.0f;
                    if (le || he) d[j] = true;
                    else          b[j] = (b[j] + 1u) & bmask;
                }
            }
        }
    } else {
        for (unsigned i = tid; i < (unsigned)N; i += stride) {
            uint32_t key = key32((uint32_t)data[i],
                                 (uint32_t)data[(size_t)N + i],
                                 (uint32_t)data[2 * (size_t)N + i]);
            uint64_t mix = mix64(key);
            uint32_t w  = bloom[(uint32_t)(mix >> 32) & BLOOM_MASK];
            uint32_t bm = (1u << ((mix >> 46) & 31u)) | (1u << ((mix >> 51) & 31u));
            if ((w & bm) != bm) continue;
            probe_pairs(key, (unsigned)mix & bmask, tb, bmask, out);
        }
    }
}

extern "C" void kernel_launch(void* const* d_in, const int* in_sizes, int n_in,
                              void* d_out, int out_size, void* d_ws, size_t ws_size,
                              hipStream_t stream) {
    const int* heads = (const int*)d_in[0];
    const int* rels  = (const int*)d_in[1];
    const int* tails = (const int*)d_in[2];
    const int* data  = (const int*)d_in[3];   // [3, N] row-major int32
    float* out = (float*)d_out;

    const int Q = in_sizes[0];
    const int N = in_sizes[3] / 3;

    // ws layout: table (pow2 entries) then bloom (64 KB).
    size_t cap = 1ull << 18;                  // 2 MB, load factor ~0.38 @ Q=100K
    if (cap * 8 + BLOOM_WORDS * 4 > ws_size) cap = 1ull << 17;
    if (cap * 8 + BLOOM_WORDS * 4 > ws_size) return;  // can't run
    unsigned tmask = (unsigned)(cap - 1);
    unsigned long long* table = (unsigned long long*)d_ws;
    uint32_t* g_bloom = (uint32_t*)((char*)d_ws + cap * 8);

    {   // 1) clear table + bloom (capture-safe: kernel, no runtime APIs)
        unsigned n_table4 = (unsigned)(cap / 2);        // 2 u64 per uint4
        unsigned n_bloom4 = BLOOM_WORDS / 4;
        unsigned n = n_table4 > n_bloom4 ? n_table4 : n_bloom4;
        dim3 block(256), grid((n + 255) / 256);
        clear_ws<<<grid, block, 0, stream>>>((uint4*)table, n_table4,
                                             (uint4*)g_bloom, n_bloom4);
    }
    {   // 2) insert queries: bloom bits + table entries + out := -5
        dim3 block(256), grid((Q + 255) / 256);
        insert_queries<<<grid, block, 0, stream>>>(heads, rels, tails, table, tmask,
                                                   g_bloom, out, Q);
    }
    {   // 3) scan data: 8-wide batched bloom + batched bucket rounds.
        // 512 blocks x 512 threads = 2 resident blocks/CU (LDS-bound).
        dim3 block(512), grid(512);
        scan_data<<<grid, block, 0, stream>>>(data, N, table, tmask, g_bloom, out);
    }
}

// Round 5
// 217.557 us; speedup vs baseline: 1.1125x; 1.1125x over previous
//
#include <hip/hip_runtime.h>
#include <stdint.h>

// PerfeCT membership test — out[i] = +5 if query triple i's wrapped-int32 KEY
// matches any data triple's wrapped-int32 KEY, else -5.
//
// NUMERICS (verified absmax 0 across rounds): JAX x64 disabled -> buffers are
// INT32; the reference computes _triple_key in int32, which WRAPS. Membership
// = equality of wrapped 32-bit keys.
//
// PERF history:
//  R0: probe batching + bucketized 16B probes + nt stream: scan 77 -> ~63us.
//  R2: explicit stream pipeline: NEUTRAL (compiler already hoists).
//  R3: 8-wide + speculative 2-bucket, lb(512,4): allocator force-fit 64 VGPR
//      -> 31MB scratch spills on the critical chain. 72us.
//  R4: 8-wide spill-free at 16 waves/CU: 76us. Clean A/B vs R1: occupancy
//      (32 waves) beats 8-wide batching. MODEL: scan is bounded by per-CU
//      vector-memory line throughput (~6.5cy/64B line; fits prev session's
//      121us no-bloom scan AND the 6.3TB/s copy ceiling): 1.9M stream lines
//      + 1.3M probe lines ~= 34us ideal; rest = VALU (mix64 ~28 ops/triple,
//      ~18us) + unhidden latency.
//  R5: R1 shell (1024 thr, 4-wide, 32 waves/CU, VGPR<=64) + Murmur3 32-bit
//      finalizer replacing mix64 (8 VALU ops vs 28). Bloom/bucket indices
//      carved from one mixed u32; insert+scan share the function.

#define EMPTY64     0xFFFFFFFFFFFFFFFFULL
#define BLOOM_WORDS 16384u                 // 64 KB, power of two
#define BLOOM_MASK  (BLOOM_WORDS - 1u)

typedef unsigned int       v4u   __attribute__((ext_vector_type(4)));
typedef unsigned long long v2u64 __attribute__((ext_vector_type(2)));

__device__ __forceinline__ uint32_t key32(uint32_t h, uint32_t r, uint32_t t) {
    return (h * 15000u + r) * 15000u + t;  // int32 wrap semantics via uint32
}

// Murmur3 fmix32 — full-avalanche 32-bit mix, 2 muls + 3 xor-shifts.
__device__ __forceinline__ uint32_t mix32(uint32_t x) {
    x ^= x >> 16; x *= 0x85ebca6bu;
    x ^= x >> 13; x *= 0xc2b2ae35u;
    x ^= x >> 16;
    return x;
}

// Shared hash-field extraction (insert and scan MUST agree):
//   bloom word  = bits 18..31, bloom bits = bits 13..17 and 8..12,
//   bucket      = low bits (mask bmask).
__device__ __forceinline__ uint32_t bloom_word_idx(uint32_t m) { return (m >> 18) & BLOOM_MASK; }
__device__ __forceinline__ uint32_t bloom_bits(uint32_t m) {
    return (1u << ((m >> 13) & 31u)) | (1u << ((m >> 8) & 31u));
}

// Clear table (to EMPTY) and bloom (to 0) with 16B stores.
__global__ void clear_ws(uint4* __restrict__ table4, unsigned n_table4,
                         uint4* __restrict__ bloom4, unsigned n_bloom4) {
    unsigned i = blockIdx.x * blockDim.x + threadIdx.x;
    if (i < n_table4) table4[i] = make_uint4(~0u, ~0u, ~0u, ~0u);
    if (i < n_bloom4) bloom4[i] = make_uint4(0u, 0u, 0u, 0u);
}

__global__ void insert_queries(const int* __restrict__ heads,
                               const int* __restrict__ rels,
                               const int* __restrict__ tails,
                               unsigned long long* __restrict__ table,
                               unsigned tmask,
                               uint32_t* __restrict__ g_bloom,
                               float* __restrict__ out,
                               int Q) {
    int i = blockIdx.x * blockDim.x + threadIdx.x;
    if (i >= Q) return;
    out[i] = -5.0f;  // default: not a member
    uint32_t key = key32((uint32_t)heads[i], (uint32_t)rels[i], (uint32_t)tails[i]);
    uint32_t m = mix32(key);
    atomicOr(&g_bloom[bloom_word_idx(m)], bloom_bits(m));
    // open-addressing insert, BUCKET-ALIGNED start (even slot) so the scan
    // can walk aligned 16B pairs. Slots only go EMPTY->occupied, so every
    // entry's probe path stays occupied -> pair-walk terminating at the first
    // EMPTY-containing bucket (evaluated inclusively) reaches all duplicates.
    uint64_t entry = (uint64_t)key | ((uint64_t)(unsigned)i << 32);
    unsigned slot = (m & (tmask >> 1)) << 1;                 // even
    for (unsigned step = 0; step <= tmask; ++step) {         // bounded
        if (atomicCAS(&table[slot], EMPTY64, (unsigned long long)entry) == EMPTY64) break;
        slot = (slot + 1u) & tmask;
    }
}

// Walk aligned 2-entry buckets from bucket b until a bucket containing an
// EMPTY slot; write +5 for every matching entry (dup queries each inserted).
__device__ __forceinline__ void probe_pairs(uint32_t key, unsigned b,
                                            const v2u64* __restrict__ tb,
                                            unsigned bmask,
                                            float* __restrict__ out) {
    for (unsigned step = 0; step <= bmask; ++step) {         // bounded
        v2u64 e = tb[b];
        bool le = (e.x == EMPTY64), he = (e.y == EMPTY64);
        if (!le && (uint32_t)e.x == key) out[e.x >> 32] = 5.0f;
        if (!he && (uint32_t)e.y == key) out[e.y >> 32] = 5.0f;
        if (le || he) return;
        b = (b + 1u) & bmask;
    }
}

__global__ __launch_bounds__(1024, 8)  // force VGPR<=64: 2 blocks/CU, 32 waves
void scan_data(const int* __restrict__ data, int N,
               const unsigned long long* __restrict__ table,
               unsigned tmask,
               const uint32_t* __restrict__ g_bloom,
               float* __restrict__ out) {
    __shared__ uint32_t bloom[BLOOM_WORDS];     // 64 KB -> 2 blocks/CU
    {   // stage bloom into LDS (16B vector copies)
        const uint4* src = (const uint4*)g_bloom;
        uint4* dst = (uint4*)bloom;
        for (unsigned w = threadIdx.x; w < BLOOM_WORDS / 4; w += blockDim.x)
            dst[w] = src[w];
    }
    __syncthreads();

    const unsigned tid    = blockIdx.x * blockDim.x + threadIdx.x;
    const unsigned stride = gridDim.x * blockDim.x;
    const unsigned bmask  = tmask >> 1;                      // bucket-index mask
    const v2u64* tb = (const v2u64*)table;

    if ((N & 3) == 0) {
        const unsigned nq = (unsigned)(N >> 2);    // 4-triple groups
        const v4u* h4 = (const v4u*)data;
        const v4u* r4 = (const v4u*)(data + (size_t)N);
        const v4u* t4 = (const v4u*)(data + 2 * (size_t)N);

        for (unsigned q = tid; q < nq; q += stride) {
            // nt stream: once-read data, keep it out of L2 (protect table)
            v4u h = __builtin_nontemporal_load(&h4[q]);
            v4u r = __builtin_nontemporal_load(&r4[q]);
            v4u t = __builtin_nontemporal_load(&t4[q]);

            uint32_t k[4];
            k[0] = key32(h.x, r.x, t.x); k[1] = key32(h.y, r.y, t.y);
            k[2] = key32(h.z, r.z, t.z); k[3] = key32(h.w, r.w, t.w);

            bool d[4]; unsigned b[4];
#pragma unroll
            for (int j = 0; j < 4; ++j) {          // 4 batched LDS bloom tests
                uint32_t m  = mix32(k[j]);
                uint32_t w  = bloom[bloom_word_idx(m)];
                d[j] = (w & bloom_bits(m)) != bloom_bits(m);   // bloom reject
                b[j] = m & bmask;
            }

            // batched bucket rounds: pending 16B loads issue together, one
            // wait per round; ~10% lane survival -> ~6 active lanes/load.
            for (unsigned g = 0; g <= bmask; ++g) {
                bool any = false;
#pragma unroll
                for (int j = 0; j < 4; ++j) any = any || !d[j];
                if (!any) break;
                v2u64 e[4];
#pragma unroll
                for (int j = 0; j < 4; ++j) if (!d[j]) e[j] = tb[b[j]];
#pragma unroll
                for (int j = 0; j < 4; ++j) if (!d[j]) {
                    bool le = (e[j].x == EMPTY64), he = (e[j].y == EMPTY64);
                    if (!le && (uint32_t)e[j].x == k[j]) out[e[j].x >> 32] = 5.0f;
                    if (!he && (uint32_t)e[j].y == k[j]) out[e[j].y >> 32] = 5.0f;
                    if (le || he) d[j] = true;
                    else          b[j] = (b[j] + 1u) & bmask;
                }
            }
        }
    } else {
        for (unsigned i = tid; i < (unsigned)N; i += stride) {
            uint32_t key = key32((uint32_t)data[i],
                                 (uint32_t)data[(size_t)N + i],
                                 (uint32_t)data[2 * (size_t)N + i]);
            uint32_t m  = mix32(key);
            uint32_t w  = bloom[bloom_word_idx(m)];
            if ((w & bloom_bits(m)) != bloom_bits(m)) continue;
            probe_pairs(key, m & bmask, tb, bmask, out);
        }
    }
}

extern "C" void kernel_launch(void* const* d_in, const int* in_sizes, int n_in,
                              void* d_out, int out_size, void* d_ws, size_t ws_size,
                              hipStream_t stream) {
    const int* heads = (const int*)d_in[0];
    const int* rels  = (const int*)d_in[1];
    const int* tails = (const int*)d_in[2];
    const int* data  = (const int*)d_in[3];   // [3, N] row-major int32
    float* out = (float*)d_out;

    const int Q = in_sizes[0];
    const int N = in_sizes[3] / 3;

    // ws layout: table (pow2 entries) then bloom (64 KB).
    size_t cap = 1ull << 18;                  // 2 MB, load factor ~0.38 @ Q=100K
    if (cap * 8 + BLOOM_WORDS * 4 > ws_size) cap = 1ull << 17;
    if (cap * 8 + BLOOM_WORDS * 4 > ws_size) return;  // can't run
    unsigned tmask = (unsigned)(cap - 1);
    unsigned long long* table = (unsigned long long*)d_ws;
    uint32_t* g_bloom = (uint32_t*)((char*)d_ws + cap * 8);

    {   // 1) clear table + bloom (capture-safe: kernel, no runtime APIs)
        unsigned n_table4 = (unsigned)(cap / 2);        // 2 u64 per uint4
        unsigned n_bloom4 = BLOOM_WORDS / 4;
        unsigned n = n_table4 > n_bloom4 ? n_table4 : n_bloom4;
        dim3 block(256), grid((n + 255) / 256);
        clear_ws<<<grid, block, 0, stream>>>((uint4*)table, n_table4,
                                             (uint4*)g_bloom, n_bloom4);
    }
    {   // 2) insert queries: bloom bits + table entries + out := -5
        dim3 block(256), grid((Q + 255) / 256);
        insert_queries<<<grid, block, 0, stream>>>(heads, rels, tails, table, tmask,
                                                   g_bloom, out, Q);
    }
    {   // 3) scan data: LDS bloom prefilter + batched bucket rounds.
        // 512 blocks x 1024 threads = 2 resident blocks/CU, 32 waves/CU.
        dim3 block(1024), grid(512);
        scan_data<<<grid, block, 0, stream>>>(data, N, table, tmask, g_bloom, out);
    }
}